// Round 11
// baseline (345.392 us; speedup 1.0000x reference)
//
#include <hip/hip_runtime.h>
#include <hip/hip_bf16.h>

#define NPTS 4096
#define BATCH 4
#define BN (BATCH * NPTS)
#define DMODEL 128
#define DPTS 64
#define KNBR 16
#define SWS 136   // padded LDS row stride in bf16 elements

typedef unsigned short u16;
typedef unsigned int u32;
typedef unsigned long long u64;
typedef short bh8 __attribute__((ext_vector_type(8)));
typedef float f32x4 __attribute__((ext_vector_type(4)));

__device__ __forceinline__ float bfu(u16 u) {
    union { u32 i; float f; } c; c.i = ((u32)u) << 16; return c.f;
}
__device__ __forceinline__ u16 f2u(float x) {   // f32->bf16 RNE
    u32 u = __float_as_uint(x);
    u32 r = u + 0x7FFFu + ((u >> 16) & 1u);
    return (u16)(r >> 16);
}
__device__ __forceinline__ u32 pack2(float a, float b) {
    return (u32)f2u(a) | ((u32)f2u(b) << 16);
}
// mode 0: inputs bf16; mode 1: inputs f32. Runtime-uniform, staging paths only.
__device__ __forceinline__ float ldr(const void* p, long i, int mode) {
    return mode == 0 ? bfu(((const u16*)p)[i]) : ((const float*)p)[i];
}
__device__ __forceinline__ void str(void* p, long i, float v, int mode) {
    if (mode == 0) ((u16*)p)[i] = f2u(v);
    else ((float*)p)[i] = v;
}
// Inline dtype detect: bf16 data has ~0 wild exponent fields; f32-as-u16 has ~84%.
__device__ __forceinline__ int detect_mode(const void* Wq) {
    const u16* w = (const u16*)Wq;
    int lane = threadIdx.x & 63;
    int tot = 0;
#pragma unroll
    for (int r = 0; r < 4; ++r) {
        unsigned e = (w[lane + r * 64] >> 7) & 0xFFu;
        bool wild = (e >= 132u) || (e > 0u && e <= 90u);
        tot += (int)__popcll(__ballot(wild));
    }
    return tot > 32 ? 1 : 0;
}

// ---------------- prep: weight transposes into MFMA B-layouts ------------------------
__global__ __launch_bounds__(256) void prep_kernel(
    const void* __restrict__ Wd2, const void* __restrict__ Wg1, const void* __restrict__ Wg2,
    const void* __restrict__ Wo, const void* __restrict__ Wq, const void* __restrict__ Wk,
    const void* __restrict__ Wv, const void* __restrict__ Wf1,
    u16* __restrict__ WdT2, u16* __restrict__ WgT1, u16* __restrict__ WgT2,
    u16* __restrict__ WoT, u16* __restrict__ WqT, u16* __restrict__ WkT,
    u16* __restrict__ WvT, u16* __restrict__ WfT) {
    int mode = detect_mode(Wq);
    int gid = blockIdx.x * 256 + threadIdx.x;
    if (gid < 6 * 16384) {
        int m = gid >> 14, o = gid & 16383;
        int n = o >> 7, i = o & 127;
        const void* W = (m == 0) ? Wd2 : (m == 1) ? Wg1 : (m == 2) ? Wg2
                      : (m == 3) ? Wq  : (m == 4) ? Wk  : Wv;
        u16* D = (m == 0) ? WdT2 : (m == 1) ? WgT1 : (m == 2) ? WgT2
               : (m == 3) ? WqT  : (m == 4) ? WkT  : WvT;
        D[o] = f2u(ldr(W, (long)i * 128 + n, mode));           // W^T[n][i]
    } else if (gid < 6 * 16384 + 8192) {
        int o = gid - 6 * 16384;
        int n = o >> 6, k2 = o & 63;
        WfT[o] = f2u(ldr(Wf1, (long)k2 * 128 + n, mode));      // Wf1^T[n][k]
    } else if (gid < 6 * 16384 + 16384) {
        int o2 = gid - 6 * 16384 - 8192;
        int col = o2 >> 7, i = o2 & 127;
        WoT[o2] = f2u(ldr(Wo, (long)i * 64 + col, mode));      // Wo^T[col][i]
    }
}

// ---------------- qkv: MFMA, 64 points/block, 4 waves, B from global ----------------
__global__ __launch_bounds__(256) void qkv_kernel(
    const void* __restrict__ feat, const void* __restrict__ bf1v, const void* __restrict__ WqRaw,
    const u16* __restrict__ WfT, const u16* __restrict__ WqT,
    const u16* __restrict__ WkT, const u16* __restrict__ WvT,
    u16* __restrict__ qw, u16* __restrict__ kfw, u16* __restrict__ vfw) {
    int mode = detect_mode(WqRaw);
    __shared__ __align__(16) u16 sFeat[64 * 72];
    __shared__ __align__(16) u16 sF[64 * SWS];
    const int t = threadIdx.x;
    const int p0 = blockIdx.x * 64;
    const int lane = t & 63, w = t >> 6;
    const int rg = (w & 1) * 32, cg = (w >> 1) * 64;
    const int lm = lane & 15, lq = lane >> 4;

    for (int i = t; i < 512; i += 256) {       // stage feat tile [64x64]
        int r = i >> 3, c8 = i & 7;
        u16 tmp[8];
        if (mode == 0) {
            *(uint4*)tmp = *((const uint4*)feat + (long)(p0 + r) * 8 + c8);
        } else {
            const float* fp = (const float*)feat + (long)(p0 + r) * 64 + c8 * 8;
#pragma unroll
            for (int u = 0; u < 8; ++u) tmp[u] = f2u(fp[u]);
        }
        *(uint4*)(sFeat + r * 72 + c8 * 8) = *(uint4*)tmp;
    }
    __syncthreads();

    // GEMM1: f = feat @ Wf1 + bf1 -> sF   (B from global WfT, stride 64)
    {
        f32x4 acc[2][4];
#pragma unroll
        for (int rt = 0; rt < 2; ++rt)
#pragma unroll
            for (int ct = 0; ct < 4; ++ct) { acc[rt][ct][0]=0.f; acc[rt][ct][1]=0.f; acc[rt][ct][2]=0.f; acc[rt][ct][3]=0.f; }
#pragma unroll
        for (int kk = 0; kk < 2; ++kk) {
            const int ko = kk * 32 + lq * 8;
            bh8 a0 = *(const bh8*)(sFeat + (rg + lm) * 72 + ko);
            bh8 a1 = *(const bh8*)(sFeat + (rg + 16 + lm) * 72 + ko);
            bh8 bq[4];
#pragma unroll
            for (int ct = 0; ct < 4; ++ct)
                bq[ct] = *(const bh8*)(WfT + (long)(cg + ct * 16 + lm) * 64 + ko);
#pragma unroll
            for (int ct = 0; ct < 4; ++ct) {
                acc[0][ct] = __builtin_amdgcn_mfma_f32_16x16x32_bf16(a0, bq[ct], acc[0][ct], 0, 0, 0);
                acc[1][ct] = __builtin_amdgcn_mfma_f32_16x16x32_bf16(a1, bq[ct], acc[1][ct], 0, 0, 0);
            }
        }
#pragma unroll
        for (int rt = 0; rt < 2; ++rt)
#pragma unroll
            for (int ct = 0; ct < 4; ++ct) {
                const int col = cg + ct * 16 + lm;
                const float bj = ldr(bf1v, col, mode);
#pragma unroll
                for (int r4 = 0; r4 < 4; ++r4) {
                    int row = rg + rt * 16 + lq * 4 + r4;
                    u32 u = (u32)f2u(acc[rt][ct][r4] + bj);
                    u32 o = __shfl_xor(u, 1);
                    if ((lane & 1) == 0)
                        *(u32*)(sF + row * SWS + col) = u | (o << 16);
                }
            }
    }
    __syncthreads();

    // GEMM2-4: q/k/v = f @ W   (B from global, stride 128)
    const u16* Ws[3] = {WqT, WkT, WvT};
    u16* Os[3] = {qw, kfw, vfw};
#pragma unroll 1
    for (int m = 0; m < 3; ++m) {
        f32x4 acc[2][4];
#pragma unroll
        for (int rt = 0; rt < 2; ++rt)
#pragma unroll
            for (int ct = 0; ct < 4; ++ct) { acc[rt][ct][0]=0.f; acc[rt][ct][1]=0.f; acc[rt][ct][2]=0.f; acc[rt][ct][3]=0.f; }
#pragma unroll
        for (int kk = 0; kk < 4; ++kk) {
            const int ko = kk * 32 + lq * 8;
            bh8 a0 = *(const bh8*)(sF + (rg + lm) * SWS + ko);
            bh8 a1 = *(const bh8*)(sF + (rg + 16 + lm) * SWS + ko);
            bh8 bq[4];
#pragma unroll
            for (int ct = 0; ct < 4; ++ct)
                bq[ct] = *(const bh8*)(Ws[m] + (long)(cg + ct * 16 + lm) * 128 + ko);
#pragma unroll
            for (int ct = 0; ct < 4; ++ct) {
                acc[0][ct] = __builtin_amdgcn_mfma_f32_16x16x32_bf16(a0, bq[ct], acc[0][ct], 0, 0, 0);
                acc[1][ct] = __builtin_amdgcn_mfma_f32_16x16x32_bf16(a1, bq[ct], acc[1][ct], 0, 0, 0);
            }
        }
#pragma unroll
        for (int rt = 0; rt < 2; ++rt)
#pragma unroll
            for (int ct = 0; ct < 4; ++ct) {
                const int col = cg + ct * 16 + lm;
#pragma unroll
                for (int r4 = 0; r4 < 4; ++r4) {
                    int row = rg + rt * 16 + lq * 4 + r4;
                    u32 u = (u32)f2u(acc[rt][ct][r4]);
                    u32 o = __shfl_xor(u, 1);
                    if ((lane & 1) == 0)
                        *(u32*)(Os[m] + (long)(p0 + row) * DMODEL + col) = u | (o << 16);
                }
            }
    }
}

// ---- 4-wave MFMA phase: D[64x128] = sIn @ Bglobal (+bias, opt relu) -> sOut packed
__device__ __forceinline__ void mfma4(const u16* sIn, const u16* __restrict__ Bg,
                                      const float* bias, bool dorelu,
                                      u16* sOut, int t) {
    const int lane = t & 63, w = t >> 6;
    const int rg = (w & 1) * 32, cg = (w >> 1) * 64;
    const int lm = lane & 15, lq = lane >> 4;
    f32x4 acc[2][4];
#pragma unroll
    for (int rt = 0; rt < 2; ++rt)
#pragma unroll
        for (int ct = 0; ct < 4; ++ct) { acc[rt][ct][0]=0.f; acc[rt][ct][1]=0.f; acc[rt][ct][2]=0.f; acc[rt][ct][3]=0.f; }
#pragma unroll
    for (int kk = 0; kk < 4; ++kk) {
        const int ko = kk * 32 + lq * 8;
        bh8 a0 = *(const bh8*)(sIn + (rg + lm) * SWS + ko);
        bh8 a1 = *(const bh8*)(sIn + (rg + 16 + lm) * SWS + ko);
        bh8 bq[4];
#pragma unroll
        for (int ct = 0; ct < 4; ++ct)
            bq[ct] = *(const bh8*)(Bg + (long)(cg + ct * 16 + lm) * 128 + ko);
#pragma unroll
        for (int ct = 0; ct < 4; ++ct) {
            acc[0][ct] = __builtin_amdgcn_mfma_f32_16x16x32_bf16(a0, bq[ct], acc[0][ct], 0, 0, 0);
            acc[1][ct] = __builtin_amdgcn_mfma_f32_16x16x32_bf16(a1, bq[ct], acc[1][ct], 0, 0, 0);
        }
    }
#pragma unroll
    for (int rt = 0; rt < 2; ++rt)
#pragma unroll
        for (int ct = 0; ct < 4; ++ct) {
            const int col = cg + ct * 16 + lm;
            const float bj = bias[col];
#pragma unroll
            for (int r4 = 0; r4 < 4; ++r4) {
                int row = rg + rt * 16 + lq * 4 + r4;
                float v = acc[rt][ct][r4] + bj;
                if (dorelu) v = fmaxf(v, 0.f);
                u32 u = (u32)f2u(v);
                u32 o = __shfl_xor(u, 1);
                if ((lane & 1) == 0)
                    *(u32*)(sOut + row * SWS + col) = u | (o << 16);
            }
        }
}

// ---------------- fused knn+att: 4 points/block, 4 waves, 38.9KB LDS ----------------
// Phase 1: stage 32KB bf16 cloud, wave-per-point top-16 scan (u64 packed key|idx),
//          2 candidates/lane/ballot. Phase 2: att pipeline, G/logits ping-pong
//          sA<->sPE; vpe packed bf16 in 16 regs; two-pass softmax (no lg arrays).
#define ATT_SA 0
#define ATT_SPE 17408
#define ATT_SREL 34816
#define ATT_SBIAS 35840
#define ATT_SQ 37376
#define SMEM_BYTES 38400

__global__ __launch_bounds__(256, 4) void fused_kernel(
    const void* __restrict__ xyz, const void* __restrict__ feat,
    const void* __restrict__ Wd1, const void* __restrict__ bd1, const void* __restrict__ bd2,
    const void* __restrict__ bg1, const void* __restrict__ bg2, const void* __restrict__ bo,
    const void* __restrict__ WqRaw,
    const u16* __restrict__ WdT2, const u16* __restrict__ WgT1, const u16* __restrict__ WgT2,
    const u16* __restrict__ WoT,
    const u16* __restrict__ qw, const u16* __restrict__ kfw, const u16* __restrict__ vfw,
    void* __restrict__ out) {
    int mode = detect_mode(WqRaw);
    __shared__ __align__(16) char smem[SMEM_BYTES];
    __shared__ int sIdx[64];
    u16* sXyz = (u16*)smem;                              // knn view: [4096][4] u16, 32KB
    u16* sA   = (u16*)(smem + ATT_SA);                   // att views
    u16* sPE  = (u16*)(smem + ATT_SPE);
    float (*sRel)[4] = (float(*)[4])(smem + ATT_SREL);
    float* sBias = (float*)(smem + ATT_SBIAS);
    u16* sQ   = (u16*)(smem + ATT_SQ);

    const int t = threadIdx.x, lane = t & 63, w = t >> 6;
    const int lm = lane & 15, lq = lane >> 4;
    const int p0 = blockIdx.x * 4;
    const long bbase = (long)(p0 >> 12) * NPTS;
    const long xb = bbase * 3;

    // ---- phase 1a: stage cloud as packed bf16 {x|y<<16, z}
    for (int m = t; m < NPTS; m += 256) {
        float gx = ldr(xyz, xb + m * 3 + 0, mode);
        float gy = ldr(xyz, xb + m * 3 + 1, mode);
        float gz = ldr(xyz, xb + m * 3 + 2, mode);
        uint2 pk;
        pk.x = (u32)f2u(gx) | ((u32)f2u(gy) << 16);
        pk.y = (u32)f2u(gz);
        *(uint2*)(sXyz + m * 4) = pk;
    }
    __syncthreads();

    // ---- phase 1b: scan. Wave w = point p0+w. 2 candidates/lane/ballot.
    {
        const int pl = (p0 & (NPTS - 1)) + w;
        uint2 qv = *(const uint2*)(sXyz + pl * 4);
        const float px = __uint_as_float(qv.x << 16);
        const float py = __uint_as_float(qv.x & 0xFFFF0000u);
        const float pz = __uint_as_float(qv.y << 16);
        u64 kv = ~0ull;
        u32 Tu = 0xFFFFFFFFu;
        uint2 cd0 = *(const uint2*)(sXyz + lane * 4);
        uint2 cd1 = *(const uint2*)(sXyz + (64 + lane) * 4);
#pragma unroll 1
        for (int it = 0; it < NPTS / 128; ++it) {
            uint2 c0 = cd0, c1 = cd1;
            if (it < NPTS / 128 - 1) {
                cd0 = *(const uint2*)(sXyz + ((it + 1) * 128 + lane) * 4);
                cd1 = *(const uint2*)(sXyz + ((it + 1) * 128 + 64 + lane) * 4);
            }
            float cx0 = __uint_as_float(c0.x << 16);
            float cy0 = __uint_as_float(c0.x & 0xFFFF0000u);
            float cz0 = __uint_as_float(c0.y << 16);
            float cx1 = __uint_as_float(c1.x << 16);
            float cy1 = __uint_as_float(c1.x & 0xFFFF0000u);
            float cz1 = __uint_as_float(c1.y << 16);
            float k0 = fmaf(px * cx0 + py * cy0 + pz * cz0, -2.f,
                            cx0 * cx0 + cy0 * cy0 + cz0 * cz0);
            float k1 = fmaf(px * cx1 + py * cy1 + pz * cz1, -2.f,
                            cx1 * cx1 + cy1 * cy1 + cz1 * cz1);
            u32 u0 = __float_as_uint(k0); u0 ^= (u32)((int)u0 >> 31) | 0x80000000u;
            u32 u1 = __float_as_uint(k1); u1 ^= (u32)((int)u1 >> 31) | 0x80000000u;
            u32 umin = (u0 < u1) ? u0 : u1;
            unsigned long long mask = __ballot(umin < Tu);
            const int ibase = it * 128;
            while (mask) {
                int l = __ffsll(mask) - 1;
                mask &= mask - 1;
                u32 a0 = __builtin_amdgcn_readlane(u0, l);
                u32 a1 = __builtin_amdgcn_readlane(u1, l);
                if (a0 < Tu) {
                    u64 cand = ((u64)a0 << 32) | (u32)(ibase + l);
                    u64 prev = __shfl_up(kv, 1);
                    if (lane == 0) prev = 0;
                    kv = (prev > cand) ? prev : ((kv > cand) ? cand : kv);
                    Tu = __builtin_amdgcn_readlane((u32)(kv >> 32), 15);
                }
                if (a1 < Tu) {
                    u64 cand = ((u64)a1 << 32) | (u32)(ibase + 64 + l);
                    u64 prev = __shfl_up(kv, 1);
                    if (lane == 0) prev = 0;
                    kv = (prev > cand) ? prev : ((kv > cand) ? cand : kv);
                    Tu = __builtin_amdgcn_readlane((u32)(kv >> 32), 15);
                }
            }
        }
        if (lane < 16) sIdx[w * 16 + lane] = (int)(u32)kv;
    }
    __syncthreads();                               // scans done; sIdx visible

    // ---- phase 2 setup: biases, q, rel (rel from the LDS cloud — still intact)
    for (int i = t; i < 384; i += 256) {
        const void* b = (i < 128) ? bd2 : (i < 256) ? bg1 : bg2;
        sBias[i] = ldr(b, i & 127, mode);
    }
    ((u32*)sQ)[t] = ((const u32*)(qw + (long)p0 * DMODEL))[t];
    const int ch = 2 * lane;
    const float wd0a = ldr(Wd1, ch, mode),       wd0b = ldr(Wd1, ch + 1, mode);
    const float wd1a = ldr(Wd1, 128 + ch, mode), wd1b = ldr(Wd1, 128 + ch + 1, mode);
    const float wd2a = ldr(Wd1, 256 + ch, mode), wd2b = ldr(Wd1, 256 + ch + 1, mode);
    const float bd1a = ldr(bd1, ch, mode),       bd1b = ldr(bd1, ch + 1, mode);
    if (t < 64) {
        int pl2 = (p0 & (NPTS - 1)) + (t >> 4);
        uint2 pv = *(const uint2*)(sXyz + pl2 * 4);
        uint2 nv = *(const uint2*)(sXyz + sIdx[t] * 4);
        sRel[t][0] = __uint_as_float(pv.x << 16)          - __uint_as_float(nv.x << 16);
        sRel[t][1] = __uint_as_float(pv.x & 0xFFFF0000u)  - __uint_as_float(nv.x & 0xFFFF0000u);
        sRel[t][2] = __uint_as_float(pv.y << 16)          - __uint_as_float(nv.y << 16);
    }
    __syncthreads();                              // sRel ready; cloud reads done

    // H1 = relu(rel@Wd1+bd1) -> sA (wave w: rows w*16..+15, channel pair ch)
#pragma unroll
    for (int i = 0; i < 16; ++i) {
        int r = w * 16 + i;
        float4 rl = *(const float4*)sRel[r];
        float h0 = fmaxf(bd1a + rl.x * wd0a + rl.y * wd1a + rl.z * wd2a, 0.f);
        float h1 = fmaxf(bd1b + rl.x * wd0b + rl.y * wd1b + rl.z * wd2b, 0.f);
        *(u32*)(sA + r * SWS + ch) = pack2(h0, h1);
    }
    __syncthreads();
    mfma4(sA, WdT2, sBias, false, sPE, t);        // PE = H1@Wd2+bd2 -> sPE
    __syncthreads();                              // sPE ready; PE's sA reads done

    // A = q - kf + pe -> sA ; vpe = vf + pe -> 16 packed-bf16 regs
    u32 vpeP[16];
#pragma unroll
    for (int i = 0; i < 16; ++i) {
        int r = w * 16 + i;
        long nbase = (bbase + sIdx[r]) * (long)DMODEL + ch;
        u32 kv2 = *(const u32*)(kfw + nbase);
        u32 vv2 = *(const u32*)(vfw + nbase);
        u32 qv2 = *(const u32*)(sQ + (r >> 4) * DMODEL + ch);
        u32 pe2 = *(const u32*)(sPE + r * SWS + ch);
        float pa = bfu((u16)pe2), pb = bfu((u16)(pe2 >> 16));
        vpeP[i] = pack2(bfu((u16)vv2) + pa, bfu((u16)(vv2 >> 16)) + pb);
        float a0 = bfu((u16)qv2) - bfu((u16)kv2) + pa;
        float a1 = bfu((u16)(qv2 >> 16)) - bfu((u16)(kv2 >> 16)) + pb;
        *(u32*)(sA + r * SWS + ch) = pack2(a0, a1);
    }
    __syncthreads();                              // sA(A) ready; sPE dead
    mfma4(sA, WgT1, sBias + 128, true, sPE, t);   // G = relu(A@Wg1+bg1) -> sPE
    __syncthreads();                              // sPE(G) ready; G's sA reads done
    mfma4(sPE, WgT2, sBias + 256, false, sA, t);  // logits = G@Wg2+bg2 -> sA
    __syncthreads();                              // sA(logits) ready

    // two-pass softmax over k (logits stay in LDS; no lg register arrays)
    float res0, res1;
    {
        float mx0 = -3e38f, mx1 = -3e38f;
#pragma unroll
        for (int k = 0; k < KNBR; ++k) {
            u32 l2 = *(const u32*)(sA + (w * 16 + k) * SWS + ch);
            mx0 = fmaxf(mx0, bfu((u16)l2));
            mx1 = fmaxf(mx1, bfu((u16)(l2 >> 16)));
        }
        const float inv = 0.08838834764831845f;   // 1/sqrt(128)
        float s0 = 0.f, s1 = 0.f, r0 = 0.f, r1 = 0.f;
#pragma unroll
        for (int k = 0; k < KNBR; ++k) {
            u32 l2 = *(const u32*)(sA + (w * 16 + k) * SWS + ch);
            float e0 = __expf((bfu((u16)l2) - mx0) * inv);
            float e1 = __expf((bfu((u16)(l2 >> 16)) - mx1) * inv);
            s0 += e0; s1 += e1;
            r0 += e0 * bfu((u16)vpeP[k]);
            r1 += e1 * bfu((u16)(vpeP[k] >> 16));
        }
        res0 = r0 / s0; res1 = r1 / s1;
    }
    __syncthreads();                              // logits reads done
    *(u32*)(sA + w * SWS + ch) = pack2(res0, res1);   // res -> sA rows 0..3
    __syncthreads();

    // out[4x64] = res @ Wo + bo + shortcut (A rows 4..15 garbage -> C rows 4..15
    // garbage, discarded: C row r depends only on A row r)
    {
        const int col = w * 16 + lm;
        f32x4 acc = {0.f, 0.f, 0.f, 0.f};
#pragma unroll
        for (int kk = 0; kk < 4; ++kk) {
            const int ko = kk * 32 + lq * 8;
            bh8 aa = *(const bh8*)(sA + lm * SWS + ko);
            bh8 bb = *(const bh8*)(WoT + (long)col * DMODEL + ko);
            acc = __builtin_amdgcn_mfma_f32_16x16x32_bf16(aa, bb, acc, 0, 0, 0);
        }
        if (lq == 0) {
            float bov = ldr(bo, col, mode);
#pragma unroll
            for (int r4 = 0; r4 < 4; ++r4) {
                long p = p0 + r4;
                float v = acc[r4] + bov + ldr(feat, p * DPTS + col, mode);
                str(out, p * DPTS + col, v, mode);
            }
        }
    }
}

extern "C" void kernel_launch(void* const* d_in, const int* in_sizes, int n_in,
                              void* d_out, int out_size, void* d_ws, size_t ws_size,
                              hipStream_t stream) {
    (void)in_sizes; (void)n_in; (void)out_size; (void)ws_size;
    char* ws = (char*)d_ws;
    u16* qw   = (u16*)(ws + 256);
    u16* kfw  = qw + (long)BN * DMODEL;
    u16* vfw  = kfw + (long)BN * DMODEL;
    u16* WdT2 = vfw + (long)BN * DMODEL;
    u16* WgT1 = WdT2 + 16384;
    u16* WgT2 = WgT1 + 16384;
    u16* WoT  = WgT2 + 16384;
    u16* WqT  = WoT + 8192;
    u16* WkT  = WqT + 16384;
    u16* WvT  = WkT + 16384;
    u16* WfT  = WvT + 16384;                  // total ws ~12.7 MB

    prep_kernel<<<448, 256, 0, stream>>>(d_in[4], d_in[11], d_in[13], d_in[15],
                                         d_in[8], d_in[9], d_in[10], d_in[6],
                                         WdT2, WgT1, WgT2, WoT, WqT, WkT, WvT, WfT);
    qkv_kernel<<<BN / 64, 256, 0, stream>>>(d_in[1], d_in[7], d_in[8],
                                            WfT, WqT, WkT, WvT, qw, kfw, vfw);
    fused_kernel<<<BN / 4, 256, 0, stream>>>(d_in[0], d_in[1], d_in[2], d_in[3], d_in[5],
                                             d_in[12], d_in[14], d_in[16], d_in[8],
                                             WdT2, WgT1, WgT2, WoT,
                                             qw, kfw, vfw, d_out);
}

// Round 12
// 314.978 us; speedup vs baseline: 1.0966x; 1.0966x over previous
//
#include <hip/hip_runtime.h>
#include <hip/hip_bf16.h>

#define NPTS 4096
#define BATCH 4
#define BN (BATCH * NPTS)
#define DMODEL 128
#define DPTS 64
#define KNBR 16
#define SWS 136   // padded LDS row stride in bf16 elements

typedef unsigned short u16;
typedef unsigned int u32;
typedef unsigned long long u64;
typedef short bh8 __attribute__((ext_vector_type(8)));
typedef float f32x4 __attribute__((ext_vector_type(4)));

__device__ __forceinline__ float bfu(u16 u) {
    union { u32 i; float f; } c; c.i = ((u32)u) << 16; return c.f;
}
__device__ __forceinline__ u16 f2u(float x) {   // f32->bf16 RNE
    u32 u = __float_as_uint(x);
    u32 r = u + 0x7FFFu + ((u >> 16) & 1u);
    return (u16)(r >> 16);
}
__device__ __forceinline__ u32 pack2(float a, float b) {
    return (u32)f2u(a) | ((u32)f2u(b) << 16);
}
// mode 0: inputs bf16; mode 1: inputs f32. Runtime-uniform, staging paths only.
__device__ __forceinline__ float ldr(const void* p, long i, int mode) {
    return mode == 0 ? bfu(((const u16*)p)[i]) : ((const float*)p)[i];
}
__device__ __forceinline__ void str(void* p, long i, float v, int mode) {
    if (mode == 0) ((u16*)p)[i] = f2u(v);
    else ((float*)p)[i] = v;
}
// Inline dtype detect: bf16 data has ~0 wild exponent fields; f32-as-u16 has ~84%.
__device__ __forceinline__ int detect_mode(const void* Wq) {
    const u16* w = (const u16*)Wq;
    int lane = threadIdx.x & 63;
    int tot = 0;
#pragma unroll
    for (int r = 0; r < 4; ++r) {
        unsigned e = (w[lane + r * 64] >> 7) & 0xFFu;
        bool wild = (e >= 132u) || (e > 0u && e <= 90u);
        tot += (int)__popcll(__ballot(wild));
    }
    return tot > 32 ? 1 : 0;
}

// ---------------- prep: weight transposes into MFMA B-layouts ------------------------
__global__ __launch_bounds__(256) void prep_kernel(
    const void* __restrict__ Wd2, const void* __restrict__ Wg1, const void* __restrict__ Wg2,
    const void* __restrict__ Wo, const void* __restrict__ Wq, const void* __restrict__ Wk,
    const void* __restrict__ Wv, const void* __restrict__ Wf1,
    u16* __restrict__ WdT2, u16* __restrict__ WgT1, u16* __restrict__ WgT2,
    u16* __restrict__ WoT, u16* __restrict__ WqT, u16* __restrict__ WkT,
    u16* __restrict__ WvT, u16* __restrict__ WfT) {
    int mode = detect_mode(Wq);
    int gid = blockIdx.x * 256 + threadIdx.x;
    if (gid < 6 * 16384) {
        int m = gid >> 14, o = gid & 16383;
        int n = o >> 7, i = o & 127;
        const void* W = (m == 0) ? Wd2 : (m == 1) ? Wg1 : (m == 2) ? Wg2
                      : (m == 3) ? Wq  : (m == 4) ? Wk  : Wv;
        u16* D = (m == 0) ? WdT2 : (m == 1) ? WgT1 : (m == 2) ? WgT2
               : (m == 3) ? WqT  : (m == 4) ? WkT  : WvT;
        D[o] = f2u(ldr(W, (long)i * 128 + n, mode));           // W^T[n][i]
    } else if (gid < 6 * 16384 + 8192) {
        int o = gid - 6 * 16384;
        int n = o >> 6, k2 = o & 63;
        WfT[o] = f2u(ldr(Wf1, (long)k2 * 128 + n, mode));      // Wf1^T[n][k]
    } else if (gid < 6 * 16384 + 16384) {
        int o2 = gid - 6 * 16384 - 8192;
        int col = o2 >> 7, i = o2 & 127;
        WoT[o2] = f2u(ldr(Wo, (long)i * 64 + col, mode));      // Wo^T[col][i]
    }
}

// ---------------- qkv: MFMA, 64 points/block, 4 waves, B from global ----------------
__global__ __launch_bounds__(256) void qkv_kernel(
    const void* __restrict__ feat, const void* __restrict__ bf1v, const void* __restrict__ WqRaw,
    const u16* __restrict__ WfT, const u16* __restrict__ WqT,
    const u16* __restrict__ WkT, const u16* __restrict__ WvT,
    u16* __restrict__ qw, u16* __restrict__ kfw, u16* __restrict__ vfw) {
    int mode = detect_mode(WqRaw);
    __shared__ __align__(16) u16 sFeat[64 * 72];
    __shared__ __align__(16) u16 sF[64 * SWS];
    const int t = threadIdx.x;
    const int p0 = blockIdx.x * 64;
    const int lane = t & 63, w = t >> 6;
    const int rg = (w & 1) * 32, cg = (w >> 1) * 64;
    const int lm = lane & 15, lq = lane >> 4;

    for (int i = t; i < 512; i += 256) {       // stage feat tile [64x64]
        int r = i >> 3, c8 = i & 7;
        u16 tmp[8];
        if (mode == 0) {
            *(uint4*)tmp = *((const uint4*)feat + (long)(p0 + r) * 8 + c8);
        } else {
            const float* fp = (const float*)feat + (long)(p0 + r) * 64 + c8 * 8;
#pragma unroll
            for (int u = 0; u < 8; ++u) tmp[u] = f2u(fp[u]);
        }
        *(uint4*)(sFeat + r * 72 + c8 * 8) = *(uint4*)tmp;
    }
    __syncthreads();

    // GEMM1: f = feat @ Wf1 + bf1 -> sF   (B from global WfT, stride 64)
    {
        f32x4 acc[2][4];
#pragma unroll
        for (int rt = 0; rt < 2; ++rt)
#pragma unroll
            for (int ct = 0; ct < 4; ++ct) { acc[rt][ct][0]=0.f; acc[rt][ct][1]=0.f; acc[rt][ct][2]=0.f; acc[rt][ct][3]=0.f; }
#pragma unroll
        for (int kk = 0; kk < 2; ++kk) {
            const int ko = kk * 32 + lq * 8;
            bh8 a0 = *(const bh8*)(sFeat + (rg + lm) * 72 + ko);
            bh8 a1 = *(const bh8*)(sFeat + (rg + 16 + lm) * 72 + ko);
            bh8 bq[4];
#pragma unroll
            for (int ct = 0; ct < 4; ++ct)
                bq[ct] = *(const bh8*)(WfT + (long)(cg + ct * 16 + lm) * 64 + ko);
#pragma unroll
            for (int ct = 0; ct < 4; ++ct) {
                acc[0][ct] = __builtin_amdgcn_mfma_f32_16x16x32_bf16(a0, bq[ct], acc[0][ct], 0, 0, 0);
                acc[1][ct] = __builtin_amdgcn_mfma_f32_16x16x32_bf16(a1, bq[ct], acc[1][ct], 0, 0, 0);
            }
        }
#pragma unroll
        for (int rt = 0; rt < 2; ++rt)
#pragma unroll
            for (int ct = 0; ct < 4; ++ct) {
                const int col = cg + ct * 16 + lm;
                const float bj = ldr(bf1v, col, mode);
#pragma unroll
                for (int r4 = 0; r4 < 4; ++r4) {
                    int row = rg + rt * 16 + lq * 4 + r4;
                    u32 u = (u32)f2u(acc[rt][ct][r4] + bj);
                    u32 o = __shfl_xor(u, 1);
                    if ((lane & 1) == 0)
                        *(u32*)(sF + row * SWS + col) = u | (o << 16);
                }
            }
    }
    __syncthreads();

    // GEMM2-4: q/k/v = f @ W   (B from global, stride 128)
    const u16* Ws[3] = {WqT, WkT, WvT};
    u16* Os[3] = {qw, kfw, vfw};
#pragma unroll 1
    for (int m = 0; m < 3; ++m) {
        f32x4 acc[2][4];
#pragma unroll
        for (int rt = 0; rt < 2; ++rt)
#pragma unroll
            for (int ct = 0; ct < 4; ++ct) { acc[rt][ct][0]=0.f; acc[rt][ct][1]=0.f; acc[rt][ct][2]=0.f; acc[rt][ct][3]=0.f; }
#pragma unroll
        for (int kk = 0; kk < 4; ++kk) {
            const int ko = kk * 32 + lq * 8;
            bh8 a0 = *(const bh8*)(sF + (rg + lm) * SWS + ko);
            bh8 a1 = *(const bh8*)(sF + (rg + 16 + lm) * SWS + ko);
            bh8 bq[4];
#pragma unroll
            for (int ct = 0; ct < 4; ++ct)
                bq[ct] = *(const bh8*)(Ws[m] + (long)(cg + ct * 16 + lm) * 128 + ko);
#pragma unroll
            for (int ct = 0; ct < 4; ++ct) {
                acc[0][ct] = __builtin_amdgcn_mfma_f32_16x16x32_bf16(a0, bq[ct], acc[0][ct], 0, 0, 0);
                acc[1][ct] = __builtin_amdgcn_mfma_f32_16x16x32_bf16(a1, bq[ct], acc[1][ct], 0, 0, 0);
            }
        }
#pragma unroll
        for (int rt = 0; rt < 2; ++rt)
#pragma unroll
            for (int ct = 0; ct < 4; ++ct) {
                const int col = cg + ct * 16 + lm;
#pragma unroll
                for (int r4 = 0; r4 < 4; ++r4) {
                    int row = rg + rt * 16 + lq * 4 + r4;
                    u32 u = (u32)f2u(acc[rt][ct][r4]);
                    u32 o = __shfl_xor(u, 1);
                    if ((lane & 1) == 0)
                        *(u32*)(Os[m] + (long)(p0 + row) * DMODEL + col) = u | (o << 16);
                }
            }
    }
}

// ---- 4-wave MFMA phase: D[64x128] = sIn @ Bglobal (+bias, opt relu) -> sOut packed
// inplace=true: barrier between fragment reads and epilogue writes (sIn may == sOut).
__device__ __forceinline__ void mfma4(const u16* sIn, const u16* __restrict__ Bg,
                                      const float* bias, bool dorelu, bool inplace,
                                      u16* sOut, int t) {
    const int lane = t & 63, w = t >> 6;
    const int rg = (w & 1) * 32, cg = (w >> 1) * 64;
    const int lm = lane & 15, lq = lane >> 4;
    f32x4 acc[2][4];
#pragma unroll
    for (int rt = 0; rt < 2; ++rt)
#pragma unroll
        for (int ct = 0; ct < 4; ++ct) { acc[rt][ct][0]=0.f; acc[rt][ct][1]=0.f; acc[rt][ct][2]=0.f; acc[rt][ct][3]=0.f; }
#pragma unroll
    for (int kk = 0; kk < 4; ++kk) {
        const int ko = kk * 32 + lq * 8;
        bh8 a0 = *(const bh8*)(sIn + (rg + lm) * SWS + ko);
        bh8 a1 = *(const bh8*)(sIn + (rg + 16 + lm) * SWS + ko);
        bh8 bq[4];
#pragma unroll
        for (int ct = 0; ct < 4; ++ct)
            bq[ct] = *(const bh8*)(Bg + (long)(cg + ct * 16 + lm) * 128 + ko);
#pragma unroll
        for (int ct = 0; ct < 4; ++ct) {
            acc[0][ct] = __builtin_amdgcn_mfma_f32_16x16x32_bf16(a0, bq[ct], acc[0][ct], 0, 0, 0);
            acc[1][ct] = __builtin_amdgcn_mfma_f32_16x16x32_bf16(a1, bq[ct], acc[1][ct], 0, 0, 0);
        }
    }
    if (inplace) __syncthreads();
#pragma unroll
    for (int rt = 0; rt < 2; ++rt)
#pragma unroll
        for (int ct = 0; ct < 4; ++ct) {
            const int col = cg + ct * 16 + lm;
            const float bj = bias[col];
#pragma unroll
            for (int r4 = 0; r4 < 4; ++r4) {
                int row = rg + rt * 16 + lq * 4 + r4;
                float v = acc[rt][ct][r4] + bj;
                if (dorelu) v = fmaxf(v, 0.f);
                u32 u = (u32)f2u(v);
                u32 o = __shfl_xor(u, 1);
                if ((lane & 1) == 0)
                    *(u32*)(sOut + row * SWS + col) = u | (o << 16);
            }
        }
}

// ---------------- fused knn+att: 4 points/block, 4 waves, 38.9KB LDS ----------------
// Phase 1: stage 32KB bf16 cloud; seed top-16 via 64-lane bitonic sort of candidates
//          0..63, then 2-cand/lane ballot scan over 64..4095. Phase 2: att pipeline —
//          G/logits in-place in sA (sPE preserved), vpe recomputed at softmax so no
//          value lives across a GEMM (keeps VGPR<=64 without scratch spill).
#define ATT_SA 0
#define ATT_SPE 17408
#define ATT_SREL 34816
#define ATT_SBIAS 35840
#define ATT_SQ 37376
#define SMEM_BYTES 38400

__global__ __launch_bounds__(256, 4) void fused_kernel(
    const void* __restrict__ xyz, const void* __restrict__ feat,
    const void* __restrict__ Wd1, const void* __restrict__ bd1, const void* __restrict__ bd2,
    const void* __restrict__ bg1, const void* __restrict__ bg2, const void* __restrict__ bo,
    const void* __restrict__ WqRaw,
    const u16* __restrict__ WdT2, const u16* __restrict__ WgT1, const u16* __restrict__ WgT2,
    const u16* __restrict__ WoT,
    const u16* __restrict__ qw, const u16* __restrict__ kfw, const u16* __restrict__ vfw,
    void* __restrict__ out) {
    int mode = detect_mode(WqRaw);
    __shared__ __align__(16) char smem[SMEM_BYTES];
    __shared__ int sIdx[64];
    u16* sXyz = (u16*)smem;                              // knn view: [4096][4] u16, 32KB
    u16* sA   = (u16*)(smem + ATT_SA);                   // att views
    u16* sPE  = (u16*)(smem + ATT_SPE);
    float (*sRel)[4] = (float(*)[4])(smem + ATT_SREL);
    float* sBias = (float*)(smem + ATT_SBIAS);
    u16* sQ   = (u16*)(smem + ATT_SQ);

    const int t = threadIdx.x, lane = t & 63, w = t >> 6;
    const int lm = lane & 15, lq = lane >> 4;
    const int p0 = blockIdx.x * 4;
    const long bbase = (long)(p0 >> 12) * NPTS;
    const long xb = bbase * 3;

    // ---- phase 1a: stage cloud as packed bf16 {x|y<<16, z}
    for (int m = t; m < NPTS; m += 256) {
        float gx = ldr(xyz, xb + m * 3 + 0, mode);
        float gy = ldr(xyz, xb + m * 3 + 1, mode);
        float gz = ldr(xyz, xb + m * 3 + 2, mode);
        uint2 pk;
        pk.x = (u32)f2u(gx) | ((u32)f2u(gy) << 16);
        pk.y = (u32)f2u(gz);
        *(uint2*)(sXyz + m * 4) = pk;
    }
    __syncthreads();

    // ---- phase 1b: scan. Wave w = point p0+w.
    {
        const int pl = (p0 & (NPTS - 1)) + w;
        uint2 qv = *(const uint2*)(sXyz + pl * 4);
        const float px = __uint_as_float(qv.x << 16);
        const float py = __uint_as_float(qv.x & 0xFFFF0000u);
        const float pz = __uint_as_float(qv.y << 16);

        // seed: keys of candidates 0..63, 64-lane bitonic sort ascending (u64 key|idx)
        u64 kv;
        {
            uint2 c = *(const uint2*)(sXyz + lane * 4);
            float cx = __uint_as_float(c.x << 16);
            float cy = __uint_as_float(c.x & 0xFFFF0000u);
            float cz = __uint_as_float(c.y << 16);
            float key = fmaf(px * cx + py * cy + pz * cz, -2.f,
                             cx * cx + cy * cy + cz * cz);
            u32 uk = __float_as_uint(key);
            uk ^= (u32)((int)uk >> 31) | 0x80000000u;    // monotone float->u32
            kv = ((u64)uk << 32) | (u32)lane;
#pragma unroll
            for (int k = 2; k <= 64; k <<= 1) {
#pragma unroll
                for (int j = k >> 1; j > 0; j >>= 1) {
                    u64 other = __shfl_xor(kv, j);
                    bool keepMin = ((lane & j) == 0) == ((lane & k) == 0);
                    bool smaller = kv < other;
                    kv = (keepMin == smaller) ? kv : other;
                }
            }
        }
        u32 Tu = __builtin_amdgcn_readlane((u32)(kv >> 32), 15);

        // main loop: candidates 64..4095, 2 candidates/lane/ballot
        uint2 cd0 = *(const uint2*)(sXyz + (64 + lane) * 4);
        uint2 cd1 = *(const uint2*)(sXyz + (128 + lane) * 4);
#pragma unroll 1
        for (int it = 0; it < 32; ++it) {
            const int base = 64 + it * 128;
            uint2 c0 = cd0, c1 = cd1;
            if (it < 31) {
                int n0 = base + 128 + lane;
                int n1 = n0 + 64 > 4095 ? 4095 : n0 + 64;
                cd0 = *(const uint2*)(sXyz + n0 * 4);
                cd1 = *(const uint2*)(sXyz + n1 * 4);
            }
            float cx0 = __uint_as_float(c0.x << 16);
            float cy0 = __uint_as_float(c0.x & 0xFFFF0000u);
            float cz0 = __uint_as_float(c0.y << 16);
            float cx1 = __uint_as_float(c1.x << 16);
            float cy1 = __uint_as_float(c1.x & 0xFFFF0000u);
            float cz1 = __uint_as_float(c1.y << 16);
            float k0 = fmaf(px * cx0 + py * cy0 + pz * cz0, -2.f,
                            cx0 * cx0 + cy0 * cy0 + cz0 * cz0);
            float k1 = fmaf(px * cx1 + py * cy1 + pz * cz1, -2.f,
                            cx1 * cx1 + cy1 * cy1 + cz1 * cz1);
            u32 u0 = __float_as_uint(k0); u0 ^= (u32)((int)u0 >> 31) | 0x80000000u;
            u32 u1 = __float_as_uint(k1); u1 ^= (u32)((int)u1 >> 31) | 0x80000000u;
            if (it == 31) u1 = 0xFFFFFFFFu;              // c1 range is out of bounds
            u32 umin = (u0 < u1) ? u0 : u1;
            unsigned long long mask = __ballot(umin < Tu);
            while (mask) {
                int l = __ffsll(mask) - 1;
                mask &= mask - 1;
                u32 a0 = __builtin_amdgcn_readlane(u0, l);
                u32 a1 = __builtin_amdgcn_readlane(u1, l);
                if (a0 < Tu) {
                    u64 cand = ((u64)a0 << 32) | (u32)(base + l);
                    u64 prev = __shfl_up(kv, 1);
                    if (lane == 0) prev = 0;
                    kv = (prev > cand) ? prev : ((kv > cand) ? cand : kv);
                    Tu = __builtin_amdgcn_readlane((u32)(kv >> 32), 15);
                }
                if (a1 < Tu) {
                    u64 cand = ((u64)a1 << 32) | (u32)(base + 64 + l);
                    u64 prev = __shfl_up(kv, 1);
                    if (lane == 0) prev = 0;
                    kv = (prev > cand) ? prev : ((kv > cand) ? cand : kv);
                    Tu = __builtin_amdgcn_readlane((u32)(kv >> 32), 15);
                }
            }
        }
        if (lane < 16) sIdx[w * 16 + lane] = (int)(u32)kv;
    }
    __syncthreads();                               // scans done; sIdx visible

    // ---- phase 2 setup: biases, q, rel (rel from the LDS cloud — still intact)
    for (int i = t; i < 384; i += 256) {
        const void* b = (i < 128) ? bd2 : (i < 256) ? bg1 : bg2;
        sBias[i] = ldr(b, i & 127, mode);
    }
    ((u32*)sQ)[t] = ((const u32*)(qw + (long)p0 * DMODEL))[t];
    const int ch = 2 * lane;
    const float wd0a = ldr(Wd1, ch, mode),       wd0b = ldr(Wd1, ch + 1, mode);
    const float wd1a = ldr(Wd1, 128 + ch, mode), wd1b = ldr(Wd1, 128 + ch + 1, mode);
    const float wd2a = ldr(Wd1, 256 + ch, mode), wd2b = ldr(Wd1, 256 + ch + 1, mode);
    const float bd1a = ldr(bd1, ch, mode),       bd1b = ldr(bd1, ch + 1, mode);
    if (t < 64) {
        int pl2 = (p0 & (NPTS - 1)) + (t >> 4);
        uint2 pv = *(const uint2*)(sXyz + pl2 * 4);
        uint2 nv = *(const uint2*)(sXyz + sIdx[t] * 4);
        sRel[t][0] = __uint_as_float(pv.x << 16)          - __uint_as_float(nv.x << 16);
        sRel[t][1] = __uint_as_float(pv.x & 0xFFFF0000u)  - __uint_as_float(nv.x & 0xFFFF0000u);
        sRel[t][2] = __uint_as_float(pv.y << 16)          - __uint_as_float(nv.y << 16);
    }
    __syncthreads();                              // sRel ready; cloud reads done

    // H1 = relu(rel@Wd1+bd1) -> sA (wave w: rows w*16..+15, channel pair ch)
#pragma unroll
    for (int i = 0; i < 16; ++i) {
        int r = w * 16 + i;
        float4 rl = *(const float4*)sRel[r];
        float h0 = fmaxf(bd1a + rl.x * wd0a + rl.y * wd1a + rl.z * wd2a, 0.f);
        float h1 = fmaxf(bd1b + rl.x * wd0b + rl.y * wd1b + rl.z * wd2b, 0.f);
        *(u32*)(sA + r * SWS + ch) = pack2(h0, h1);
    }
    __syncthreads();
    mfma4(sA, WdT2, sBias, false, false, sPE, t); // PE = H1@Wd2+bd2 -> sPE
    __syncthreads();                              // sPE ready; PE's sA reads done

    // A = q - kf + pe -> sA (nothing else kept live across the GEMMs)
#pragma unroll
    for (int i = 0; i < 16; ++i) {
        int r = w * 16 + i;
        u32 kv2 = *(const u32*)(kfw + (bbase + sIdx[r]) * (long)DMODEL + ch);
        u32 qv2 = *(const u32*)(sQ + (r >> 4) * DMODEL + ch);
        u32 pe2 = *(const u32*)(sPE + r * SWS + ch);
        float a0 = bfu((u16)qv2) - bfu((u16)kv2) + bfu((u16)pe2);
        float a1 = bfu((u16)(qv2 >> 16)) - bfu((u16)(kv2 >> 16)) + bfu((u16)(pe2 >> 16));
        *(u32*)(sA + r * SWS + ch) = pack2(a0, a1);
    }
    __syncthreads();
    mfma4(sA, WgT1, sBias + 128, true, true, sA, t);   // G = relu(A@Wg1+bg1), in place
    __syncthreads();
    mfma4(sA, WgT2, sBias + 256, false, true, sA, t);  // logits = G@Wg2+bg2, in place
    __syncthreads();                              // sA(logits) ready; sPE(PE) intact

    // two-pass softmax over k; vpe = vfw + pe recomputed here (no cross-GEMM regs)
    float res0, res1;
    {
        float mx0 = -3e38f, mx1 = -3e38f;
#pragma unroll
        for (int k = 0; k < KNBR; ++k) {
            u32 l2 = *(const u32*)(sA + (w * 16 + k) * SWS + ch);
            mx0 = fmaxf(mx0, bfu((u16)l2));
            mx1 = fmaxf(mx1, bfu((u16)(l2 >> 16)));
        }
        const float inv = 0.08838834764831845f;   // 1/sqrt(128)
        float s0 = 0.f, s1 = 0.f, r0 = 0.f, r1 = 0.f;
#pragma unroll
        for (int k = 0; k < KNBR; ++k) {
            u32 l2 = *(const u32*)(sA + (w * 16 + k) * SWS + ch);
            u32 v2 = *(const u32*)(vfw + (bbase + sIdx[w * 16 + k]) * (long)DMODEL + ch);
            u32 p2 = *(const u32*)(sPE + (w * 16 + k) * SWS + ch);
            float e0 = __expf((bfu((u16)l2) - mx0) * inv);
            float e1 = __expf((bfu((u16)(l2 >> 16)) - mx1) * inv);
            s0 += e0; s1 += e1;
            r0 += e0 * (bfu((u16)v2) + bfu((u16)p2));
            r1 += e1 * (bfu((u16)(v2 >> 16)) + bfu((u16)(p2 >> 16)));
        }
        res0 = r0 / s0; res1 = r1 / s1;
    }
    __syncthreads();                              // logits reads done
    *(u32*)(sA + w * SWS + ch) = pack2(res0, res1);   // res -> sA rows 0..3
    __syncthreads();

    // out[4x64] = res @ Wo + bo + shortcut (A rows 4..15 garbage -> C rows 4..15
    // garbage, discarded: C row r depends only on A row r)
    {
        const int col = w * 16 + lm;
        f32x4 acc = {0.f, 0.f, 0.f, 0.f};
#pragma unroll
        for (int kk = 0; kk < 4; ++kk) {
            const int ko = kk * 32 + lq * 8;
            bh8 aa = *(const bh8*)(sA + lm * SWS + ko);
            bh8 bb = *(const bh8*)(WoT + (long)col * DMODEL + ko);
            acc = __builtin_amdgcn_mfma_f32_16x16x32_bf16(aa, bb, acc, 0, 0, 0);
        }
        if (lq == 0) {
            float bov = ldr(bo, col, mode);
#pragma unroll
            for (int r4 = 0; r4 < 4; ++r4) {
                long p = p0 + r4;
                float v = acc[r4] + bov + ldr(feat, p * DPTS + col, mode);
                str(out, p * DPTS + col, v, mode);
            }
        }
    }
}

extern "C" void kernel_launch(void* const* d_in, const int* in_sizes, int n_in,
                              void* d_out, int out_size, void* d_ws, size_t ws_size,
                              hipStream_t stream) {
    (void)in_sizes; (void)n_in; (void)out_size; (void)ws_size;
    char* ws = (char*)d_ws;
    u16* qw   = (u16*)(ws + 256);
    u16* kfw  = qw + (long)BN * DMODEL;
    u16* vfw  = kfw + (long)BN * DMODEL;
    u16* WdT2 = vfw + (long)BN * DMODEL;
    u16* WgT1 = WdT2 + 16384;
    u16* WgT2 = WgT1 + 16384;
    u16* WoT  = WgT2 + 16384;
    u16* WqT  = WoT + 8192;
    u16* WkT  = WqT + 16384;
    u16* WvT  = WkT + 16384;
    u16* WfT  = WvT + 16384;                  // total ws ~12.7 MB

    prep_kernel<<<448, 256, 0, stream>>>(d_in[4], d_in[11], d_in[13], d_in[15],
                                         d_in[8], d_in[9], d_in[10], d_in[6],
                                         WdT2, WgT1, WgT2, WoT, WqT, WkT, WvT, WfT);
    qkv_kernel<<<BN / 64, 256, 0, stream>>>(d_in[1], d_in[7], d_in[8],
                                            WfT, WqT, WkT, WvT, qw, kfw, vfw);
    fused_kernel<<<BN / 4, 256, 0, stream>>>(d_in[0], d_in[1], d_in[2], d_in[3], d_in[5],
                                             d_in[12], d_in[14], d_in[16], d_in[8],
                                             WdT2, WgT1, WgT2, WoT,
                                             qw, kfw, vfw, d_out);
}